// Round 2
// baseline (3254.310 us; speedup 1.0000x reference)
//
#include <hip/hip_runtime.h>

typedef unsigned short u16;
typedef unsigned int   u32;
typedef unsigned long long u64;
typedef __attribute__((ext_vector_type(4))) float f32x4;
typedef __attribute__((ext_vector_type(8))) short s16x8;
typedef __attribute__((ext_vector_type(4))) unsigned short u16x4;
typedef __attribute__((ext_vector_type(8))) unsigned short u16x8;

__device__ __forceinline__ float bf2f(u16 u) {
    u32 i = ((u32)u) << 16;
    return __builtin_bit_cast(float, i);
}
__device__ __forceinline__ u16 f2bf(float f) {  // round-nearest-even, finite inputs
    u32 i = __builtin_bit_cast(u32, f);
    u32 lsb = (i >> 16) & 1u;
    i += 0x7fffu + lsb;
    return (u16)(i >> 16);
}

// cache-bypassing (MALL-coherent) 16B load / 8B store — same visibility class
// as the agent-scope atomics used in round 1, but full width.
__device__ __forceinline__ void ld_cc16(s16x8& r, const u16* p) {
    asm volatile("global_load_dwordx4 %0, %1, off sc0 sc1" : "=v"(r) : "v"(p));
}
__device__ __forceinline__ void st_cc8(u16* p, u64 v) {
    asm volatile("global_store_dwordx2 %0, %1, off sc0 sc1" :: "v"(p), "v"(v) : "memory");
}

// ---------------------------------------------------------------------------
// prep: convert W_ih -> bf16 (row-major [1536][512]) and W_hh -> bf16 in MFMA
// B-fragment order: Wfrag[w][gate][kstep][lane][8], w=h-col-tile (32), kstep=K/32.
// ---------------------------------------------------------------------------
__global__ __launch_bounds__(256) void prep(const float* __restrict__ Wih,
                                            const float* __restrict__ Whh,
                                            u16* __restrict__ Wihb,
                                            u16* __restrict__ Wfrag) {
    int id = blockIdx.x * 256 + threadIdx.x;  // [0, 98304)
    {
        const float* s = Wih + (size_t)id * 8;
        f32x4 x0 = *(const f32x4*)s;
        f32x4 x1 = *(const f32x4*)(s + 4);
        u16x8 o;
        for (int j = 0; j < 4; ++j) { o[j] = f2bf(x0[j]); o[4 + j] = f2bf(x1[j]); }
        *(u16x8*)(Wihb + (size_t)id * 8) = o;
    }
    {
        int lane = id & 63;
        int ks   = (id >> 6) & 15;
        int wnt  = id >> 10;          // w*3 + nt
        int nt   = wnt % 3;
        int w    = wnt / 3;
        int row  = nt * 512 + w * 16 + (lane & 15);   // gh row
        int k    = ks * 32 + (lane >> 4) * 8;
        const float* s = Whh + (size_t)row * 512 + k;
        f32x4 x0 = *(const f32x4*)s;
        f32x4 x1 = *(const f32x4*)(s + 4);
        u16x8 o;
        for (int j = 0; j < 4; ++j) { o[j] = f2bf(x0[j]); o[4 + j] = f2bf(x1[j]); }
        *(u16x8*)(Wfrag + (size_t)id * 8) = o;
    }
}

// ---------------------------------------------------------------------------
// gemm_xproj: unchanged from round 1 (correct, ~100us; not the bottleneck).
// ---------------------------------------------------------------------------
__global__ __launch_bounds__(256) void gemm_xproj(const float* __restrict__ inp,
                                                  const u16* __restrict__ Wihb,
                                                  const float* __restrict__ bih,
                                                  u16* __restrict__ xp) {
    __shared__ u16 lA[128 * 64];
    __shared__ u16 lB[128 * 64];
    const int bid = blockIdx.x;
    const int mtile = bid & 255;
    const int ntile = bid >> 8;
    const int tid = threadIdx.x;
    const int l = tid & 63;
    const int wid = tid >> 6;
    const int s0 = mtile * 2;
    const int n0 = ntile * 128;

    f32x4 acc[4][4];
    for (int a = 0; a < 4; ++a)
        for (int b = 0; b < 4; ++b) acc[a][b] = (f32x4){0.f, 0.f, 0.f, 0.f};

    for (int k0 = 0; k0 < 512; k0 += 64) {
        if (k0) __syncthreads();
        for (int i = 0; i < 4; ++i) {
            int boff = (wid * 4 + i) * 1024 + l * 16;
            int r = boff >> 7;
            int kb = boff & 127;
            const char* src = (const char*)Wihb + (size_t)(n0 + r) * 1024 + (size_t)k0 * 2 + kb;
            __builtin_amdgcn_global_load_lds(
                (const __attribute__((address_space(1))) u32*)src,
                (__attribute__((address_space(3))) u32*)((char*)lB + (wid * 4 + i) * 1024),
                16, 0, 0);
        }
        for (int i = 0; i < 4; ++i) {
            int c = i * 256 + tid;
            int r = c >> 3;
            int ck = c & 7;
            int b = r & 63;
            int sl = r >> 6;
            const float* src = inp + ((size_t)(b * 512 + s0 + sl) * 512 + k0 + ck * 8);
            f32x4 x0 = *(const f32x4*)src;
            f32x4 x1 = *(const f32x4*)(src + 4);
            u16x8 o;
            for (int j = 0; j < 4; ++j) { o[j] = f2bf(x0[j]); o[4 + j] = f2bf(x1[j]); }
            *(u16x8*)(&lA[r * 64 + ck * 8]) = o;
        }
        __syncthreads();
        for (int kk = 0; kk < 2; ++kk) {
            s16x8 af[4], bf[4];
            for (int am = 0; am < 4; ++am)
                af[am] = *(const s16x8*)(&lA[((wid >> 1) * 64 + am * 16 + (l & 15)) * 64 + kk * 32 + (l >> 4) * 8]);
            for (int bn = 0; bn < 4; ++bn)
                bf[bn] = *(const s16x8*)(&lB[((wid & 1) * 64 + bn * 16 + (l & 15)) * 64 + kk * 32 + (l >> 4) * 8]);
            for (int am = 0; am < 4; ++am)
                for (int bn = 0; bn < 4; ++bn)
                    acc[am][bn] = __builtin_amdgcn_mfma_f32_16x16x32_bf16(af[am], bf[bn], acc[am][bn], 0, 0, 0);
        }
    }
    for (int am = 0; am < 4; ++am) {
        for (int bn = 0; bn < 4; ++bn) {
            int m_base = mtile * 128 + (wid >> 1) * 64 + am * 16;
            int row0 = m_base + ((l >> 4) << 2);
            int s = row0 >> 6;
            int b0 = row0 & 63;
            int n = n0 + (wid & 1) * 64 + bn * 16 + (l & 15);
            int g = n >> 9;
            int col = n & 511;
            int ww = col >> 4;
            int mt2 = b0 >> 4;
            size_t el = ((((size_t)s * 32 + ww) * 4 + mt2) * 3 + g) * 256 + l * 4;
            float bias = bih[n];
            u16x4 o;
            for (int j = 0; j < 4; ++j) o[j] = f2bf(acc[am][bn][j] + bias);
            *(u16x4*)(xp + el) = o;
        }
    }
}

// ---------------------------------------------------------------------------
// gru_scan v2: 32 WGs x 4 waves. Wave (w, mt) owns batches [mt*16, mt*16+16)
// x h-cols [w*16, w*16+16). W_hh slice held ENTIRELY IN REGISTERS (48 s16x8).
// No __syncthreads in the loop: per-wave arrival counter (target 128 waves),
// wave-local LDS transpose -> one 8B write-through h store per lane, 16x16B
// cache-bypass h loads. Output stores + next-step prefetch issued between
// barrier-arrive and spin so their latency hides in the wait window.
// ---------------------------------------------------------------------------
__global__ __launch_bounds__(256, 1) void gru_scan(const u16* __restrict__ xp,
                                                   const u16* __restrict__ Wfrag,
                                                   const float* __restrict__ bhh,
                                                   const float* __restrict__ inp,
                                                   float* __restrict__ dout,
                                                   u16* __restrict__ hbuf,
                                                   int* __restrict__ cnt) {
    const int w = blockIdx.x;      // 0..31 col tile
    const int tid = threadIdx.x;
    const int l = tid & 63;
    const int mt = tid >> 6;       // wave id = batch tile
    float* out_res = dout;
    float* out_hid = dout + (size_t)64 * 512 * 512;

    __shared__ u16 tlds[4][16][20];  // per-wave transpose tile (pad 16->20)

    // W_hh slice -> registers (fragment order: [gate][kk][lane][8])
    const u16* wsrc = Wfrag + (size_t)w * 24576;
    s16x8 wreg[3][16];
#pragma unroll
    for (int g = 0; g < 3; ++g)
#pragma unroll
        for (int kk = 0; kk < 16; ++kk)
            wreg[g][kk] = *(const s16x8*)(wsrc + (size_t)(g * 16 + kk) * 512 + l * 8);

    const float bh0 = bhh[0 * 512 + w * 16 + (l & 15)];
    const float bh1 = bhh[1 * 512 + w * 16 + (l & 15)];
    const float bh2 = bhh[2 * 512 + w * 16 + (l & 15)];
    float hold[4] = {0.f, 0.f, 0.f, 0.f};
    const int bb = mt * 16 + ((l >> 4) << 2);   // first batch row (C-fragment)
    const int c = w * 16 + (l & 15);            // h column (C-fragment)

    s16x8 af[16];
#pragma unroll
    for (int kk = 0; kk < 16; ++kk) af[kk] = (s16x8){0, 0, 0, 0, 0, 0, 0, 0};

    // prefetch t=0 x_proj + input
    const u16* xpp = xp + ((((size_t)0 * 32 + w) * 4 + mt) * 3) * 256 + l * 4;
    u16x4 xv0 = *(const u16x4*)(xpp);
    u16x4 xv1 = *(const u16x4*)(xpp + 256);
    u16x4 xv2 = *(const u16x4*)(xpp + 512);
    float inv[4];
#pragma unroll
    for (int j = 0; j < 4; ++j)
        inv[j] = inp[((size_t)(bb + j) * 512 + 0) * 512 + c];

    for (int t = 0; t < 512; ++t) {
        // all outstanding vmem (af h-loads from prev iter, prefetches) done
        asm volatile("s_waitcnt vmcnt(0)" ::: "memory");
        __builtin_amdgcn_sched_barrier(0);

        f32x4 acc0 = (f32x4){0.f, 0.f, 0.f, 0.f};
        f32x4 acc1 = (f32x4){0.f, 0.f, 0.f, 0.f};
        f32x4 acc2 = (f32x4){0.f, 0.f, 0.f, 0.f};
#pragma unroll
        for (int kk = 0; kk < 16; ++kk) {
            acc0 = __builtin_amdgcn_mfma_f32_16x16x32_bf16(af[kk], wreg[0][kk], acc0, 0, 0, 0);
            acc1 = __builtin_amdgcn_mfma_f32_16x16x32_bf16(af[kk], wreg[1][kk], acc1, 0, 0, 0);
            acc2 = __builtin_amdgcn_mfma_f32_16x16x32_bf16(af[kk], wreg[2][kk], acc2, 0, 0, 0);
        }

        float hn[4];
#pragma unroll
        for (int j = 0; j < 4; ++j) {
            float xr = bf2f(xv0[j]), xz = bf2f(xv1[j]), xn = bf2f(xv2[j]);
            float rr = 1.f / (1.f + __expf(-(xr + acc0[j] + bh0)));
            float zz = 1.f / (1.f + __expf(-(xz + acc1[j] + bh1)));
            float nx = xn + rr * (acc2[j] + bh2);
            float e2 = __expf(-2.f * nx);
            float nn = (1.f - e2) / (1.f + e2);
            float h = (1.f - zz) * nn + zz * hold[j];
            hold[j] = h;
            hn[j] = h;
        }

        if (t < 511) {
            // wave-local transpose: (4 rows x 1 col)/lane -> (1 row x 4 cols)/lane
#pragma unroll
            for (int j = 0; j < 4; ++j)
                tlds[mt][((l >> 4) << 2) + j][l & 15] = f2bf(hn[j]);
            u64 hv = *(const u64*)(&tlds[mt][l >> 2][(l & 3) * 4]);  // lgkmcnt auto
            // write-through h store (8B), drain, arrive
            u16* hw = hbuf + (size_t)((t + 1) & 1) * 32768;
            st_cc8(hw + (size_t)(mt * 16 + (l >> 2)) * 512 + w * 16 + (l & 3) * 4, hv);
            asm volatile("s_waitcnt vmcnt(0)" ::: "memory");
            if (l == 0)
                __hip_atomic_fetch_add(&cnt[t], 1, __ATOMIC_RELAXED, __HIP_MEMORY_SCOPE_AGENT);
        }

        // output stores (fly during the spin window)
#pragma unroll
        for (int j = 0; j < 4; ++j) {
            size_t oi = ((size_t)(bb + j) * 512 + t) * 512 + c;
            out_hid[oi] = hn[j];
            out_res[oi] = inv[j] + hn[j];
        }

        if (t < 511) {
            // prefetch t+1 x_proj + input (independent of h)
            const u16* xq = xp + ((((size_t)(t + 1) * 32 + w) * 4 + mt) * 3) * 256 + l * 4;
            xv0 = *(const u16x4*)(xq);
            xv1 = *(const u16x4*)(xq + 256);
            xv2 = *(const u16x4*)(xq + 512);
#pragma unroll
            for (int j = 0; j < 4; ++j)
                inv[j] = inp[((size_t)(bb + j) * 512 + t + 1) * 512 + c];

            // spin until all 128 waves arrived
            while (__hip_atomic_load(&cnt[t], __ATOMIC_RELAXED, __HIP_MEMORY_SCOPE_AGENT) < 128) {}
            __builtin_amdgcn_sched_barrier(0);

            // cache-bypass h(t+1) loads: 16 x 16B per lane
            const u16* hr = hbuf + (size_t)((t + 1) & 1) * 32768;
            const u16* hb = hr + (size_t)(mt * 16 + (l & 15)) * 512 + ((l >> 4) << 3);
#pragma unroll
            for (int kk = 0; kk < 16; ++kk)
                ld_cc16(af[kk], hb + kk * 32);
        }
    }
}

// ---------------------------------------------------------------------------
// Workspace layout (bytes):
//   [0, 4096)          barrier counters (512 ints used)   -- memset 0
//   [4096, 69632)      h double buffer 0 (bf16 64x512)
//   [69632, 135168)    h double buffer 1
//   [135168, 1708032)  Wfrag bf16 (1.5 MiB)
//   [1708032, 3280896) W_ih bf16 (1.5 MiB)
//   [3280896, ~103.9M) x_proj bf16, fragment-ordered (96 MiB)
// ---------------------------------------------------------------------------
extern "C" void kernel_launch(void* const* d_in, const int* in_sizes, int n_in,
                              void* d_out, int out_size, void* d_ws, size_t ws_size,
                              hipStream_t stream) {
    const float* inp = (const float*)d_in[0];
    const float* Wih = (const float*)d_in[1];
    const float* Whh = (const float*)d_in[2];
    const float* bih = (const float*)d_in[3];
    const float* bhh = (const float*)d_in[4];
    float* out = (float*)d_out;

    char* ws = (char*)d_ws;
    int* cnt   = (int*)ws;
    u16* hbuf  = (u16*)(ws + 4096);
    u16* Wfrag = (u16*)(ws + 135168);
    u16* Wihb  = (u16*)(ws + 1708032);
    u16* xp    = (u16*)(ws + 3280896);

    hipMemsetAsync(ws, 0, 4096, stream);  // barrier counters = 0
    hipLaunchKernelGGL(prep, dim3(384), dim3(256), 0, stream, Wih, Whh, Wihb, Wfrag);
    hipLaunchKernelGGL(gemm_xproj, dim3(3072), dim3(256), 0, stream, inp, Wihb, bih, xp);
    hipLaunchKernelGGL(gru_scan, dim3(32), dim3(256), 0, stream, xp, Wfrag, bhh, inp, out, hbuf, cnt);
}